// Round 15
// baseline (153.314 us; speedup 1.0000x reference)
//
#include <hip/hip_runtime.h>

typedef unsigned short u16;
typedef __attribute__((ext_vector_type(4))) float f32x4;
typedef __attribute__((ext_vector_type(8))) __bf16 bf16x8;
typedef __attribute__((ext_vector_type(8))) unsigned short us8;

#define NN (2048ull*2048ull)

__device__ __forceinline__ u16 f2b(float x){
  union { float f; unsigned u; } v; v.f = x;
  unsigned r = v.u + 0x7FFFu + ((v.u >> 16) & 1u);
  return (u16)(r >> 16);
}
__device__ __forceinline__ float b2f(u16 x){
  union { unsigned u; float f; } v; v.u = ((unsigned)x) << 16; return v.f;
}

// ---- fast zero of the atomic-target region (replaces pathological runtime memset) ----
__global__ __launch_bounds__(256)
void k_zero(float4* __restrict__ p, int n4){
  const float4 z = {0.f,0.f,0.f,0.f};
  for (int i = blockIdx.x*256 + threadIdx.x; i < n4; i += gridDim.x*256)
    p[i] = z;
}

// ---- fused 3-way mix of A -> A1T, A2T, BT (all transposed bf16 [2][2048][2048])
//      + fused col-sums (sA1 = colsum A1, deg2 = colsum B).
//      v9: 32m x 64n tile, grid 2048 -> 8 blocks/CU. --------------------------------
__global__ __launch_bounds__(256)
void k_mix(const float* __restrict__ A,
           const float* __restrict__ w1, const float* __restrict__ w2,
           const float* __restrict__ wl,
           u16* __restrict__ A1T, u16* __restrict__ A2T, u16* __restrict__ BT,
           float* __restrict__ sA1, float* __restrict__ deg2){
  __shared__ u16 lt[4][32][68];
  const int t = threadIdx.x;
  const int mg = t & 7, ng = t >> 3;                 // read: 8 m-groups x 32 n-groups
  const int m0 = blockIdx.x * 32, n0 = blockIdx.y * 64;
  float f[3][2][5];
  #pragma unroll
  for (int s=0;s<3;s++){
    const float* w = (s==0) ? w1 : (s==1) ? w2 : wl;
    #pragma unroll
    for (int c=0;c<2;c++){
      float m = -1e30f;
      #pragma unroll
      for (int e=0;e<5;e++) m = fmaxf(m, w[e*2+c]);
      float sum = 0.f;
      #pragma unroll
      for (int e=0;e<5;e++){ f[s][c][e] = __expf(w[e*2+c]-m); sum += f[s][c][e]; }
      float inv = 1.f/sum;
      #pragma unroll
      for (int e=0;e<5;e++) f[s][c][e] *= inv;
    }
  }

  // compute 6 (s,c) micro-tiles (2n x 4m) into registers; component j = m-dir
  ushort4 reg[6][2];
  #pragma unroll
  for (int rr=0; rr<2; ++rr){
    const int nl = ng*2 + rr;
    const size_t off = (size_t)(n0+nl)*2048 + m0 + mg*4;
    float4 a0 = *(const float4*)&A[off];
    float4 a1 = *(const float4*)&A[NN + off];
    float4 a2 = *(const float4*)&A[2*NN + off];
    float4 a3 = *(const float4*)&A[3*NN + off];
    float4 a4 = *(const float4*)&A[4*NN + off];
    float ax[4][5] = {{a0.x,a1.x,a2.x,a3.x,a4.x},
                      {a0.y,a1.y,a2.y,a3.y,a4.y},
                      {a0.z,a1.z,a2.z,a3.z,a4.z},
                      {a0.w,a1.w,a2.w,a3.w,a4.w}};
    #pragma unroll
    for (int c=0;c<2;c++){
      #pragma unroll
      for (int j=0;j<4;j++){
        float s1=0.f,s2=0.f,s3=0.f;
        #pragma unroll
        for (int e=0;e<5;e++){
          s1 += ax[j][e]*f[0][c][e];
          s2 += ax[j][e]*f[1][c][e];
          s3 += ax[j][e]*f[2][c][e];
        }
        ((u16*)&reg[0+c][rr])[j] = f2b(s1);
        ((u16*)&reg[2+c][rr])[j] = f2b(s2);
        ((u16*)&reg[4+c][rr])[j] = f2b(s3);
      }
    }
  }

  const int row = t >> 3, seg = t & 7;               // write: 32 m-rows x 8 segs (8n)

  // phase B1: A1 (c0,c1), A2 (c0,c1) -> buffers 0..3, m-major (in-reg transpose)
  #pragma unroll
  for (int sc=0; sc<4; ++sc){
    #pragma unroll
    for (int j=0;j<4;j++){
      ushort2 o;
      o.x = ((const u16*)&reg[sc][0])[j];
      o.y = ((const u16*)&reg[sc][1])[j];
      *(ushort2*)&lt[sc][mg*4+j][ng*2] = o;
    }
  }
  __syncthreads();
  // phase C1: store A1T (+sA1) and A2T -- 128B-contiguous bursts per m-row
  #pragma unroll
  for (int sc=0; sc<4; ++sc){
    u16* __restrict__ dst = (sc<2) ? A1T : A2T;
    const int c = sc & 1;
    us8 v0 = *(const us8*)&lt[sc][row][seg*8];
    u16* __restrict__ p = dst + (size_t)c*NN + (size_t)(m0+row)*2048 + n0 + seg*8;
    *(us8*)p = v0;
    if (sc < 2){
      float part = 0.f;
      #pragma unroll
      for (int q=0;q<8;q++) part += b2f(v0[q]);
      part += __shfl_xor(part, 1); part += __shfl_xor(part, 2);
      part += __shfl_xor(part, 4);
      if (seg == 0) atomicAdd(&sA1[c*2048 + m0 + row], part);
    }
  }
  __syncthreads();
  // phase B2: B (c0,c1) -> buffers 0,1
  #pragma unroll
  for (int c=0;c<2;c++){
    #pragma unroll
    for (int j=0;j<4;j++){
      ushort2 o;
      o.x = ((const u16*)&reg[4+c][0])[j];
      o.y = ((const u16*)&reg[4+c][1])[j];
      *(ushort2*)&lt[c][mg*4+j][ng*2] = o;
    }
  }
  __syncthreads();
  // phase C2: store BT (+deg2)
  #pragma unroll
  for (int c=0;c<2;c++){
    us8 v0 = *(const us8*)&lt[c][row][seg*8];
    u16* __restrict__ p = BT + (size_t)c*NN + (size_t)(m0+row)*2048 + n0 + seg*8;
    *(us8*)p = v0;
    float part = 0.f;
    #pragma unroll
    for (int q=0;q<8;q++) part += b2f(v0[q]);
    part += __shfl_xor(part, 1); part += __shfl_xor(part, 2);
    part += __shfl_xor(part, 4);
    if (seg == 0) atomicAdd(&deg2[c*2048 + m0 + row], part);
  }
}

// ---- merged: blocks 0..1023 -> deg1[c][j] = sum_k sA1[c][k]*A2T[c][j][k]
//              blocks 1024..1535 -> v1[c][n] += sum_m BT[c][m][n]*inv(deg2[c][m]) -----
__global__ __launch_bounds__(256)
void k_post1(const u16* __restrict__ A2T, const u16* __restrict__ BT,
             const float* __restrict__ sA1, const float* __restrict__ deg2,
             float* __restrict__ deg1, float* __restrict__ v1){
  const int b = blockIdx.x;
  const int t = threadIdx.x;
  if (b < 1024){
    const int g = b*4 + (t >> 6);
    const int lane = t & 63;
    const int c = g >> 11, j = g & 2047;
    const u16* __restrict__ row = A2T + (size_t)c*NN + (size_t)j*2048;
    const float* __restrict__ sv = sA1 + c*2048;
    float s = 0.f;
    #pragma unroll
    for (int it=0; it<4; ++it){
      const int k = it*512 + lane*8;
      us8 v = *(const us8*)&row[k];
      const float4 f0 = *(const float4*)&sv[k];
      const float4 f1 = *(const float4*)&sv[k+4];
      s += b2f(v[0])*f0.x + b2f(v[1])*f0.y + b2f(v[2])*f0.z + b2f(v[3])*f0.w
         + b2f(v[4])*f1.x + b2f(v[5])*f1.y + b2f(v[6])*f1.z + b2f(v[7])*f1.w;
    }
    s += __shfl_xor(s, 1);  s += __shfl_xor(s, 2);  s += __shfl_xor(s, 4);
    s += __shfl_xor(s, 8);  s += __shfl_xor(s, 16); s += __shfl_xor(s, 32);
    if (lane == 0) deg1[c*2048 + j] = s;
  } else {
    __shared__ float w[64];
    const int bx = b - 1024;
    const int x = bx & 7, y = (bx >> 3) & 31, c = bx >> 8;
    const int n = x * 256 + t;
    const int m0 = y * 64;
    if (t < 64){
      float d = deg2[c*2048 + m0 + t];
      w[t] = d > 0.f ? 1.f/d : 0.f;
    }
    __syncthreads();
    const u16* __restrict__ p = BT + (size_t)c*NN + (size_t)m0*2048 + n;
    float s = 0.f;
    #pragma unroll 4
    for (int m=0;m<64;m++)
      s += b2f(p[(size_t)m*2048]) * w[m];
    atomicAdd(&v1[c*2048 + n], s);
  }
}

// ---- weighted column-sum over rows of MT: outv[c][n] += sum_m w[m]*MT[c][m][n] -------
template<int MODE>
__global__ __launch_bounds__(256)
void k_wsum(const u16* __restrict__ MT, const float* __restrict__ va,
            const float* __restrict__ vb, float* __restrict__ outv){
  __shared__ float w[64];
  const int t = threadIdx.x;
  const int n = blockIdx.x * 256 + t;
  const int m0 = blockIdx.y * 64;
  const int c = blockIdx.z;
  if (t < 64){
    const int m = c*2048 + m0 + t;
    float x;
    if (MODE == 1){ float d = va[m]; x = (d > 0.f ? 1.f/d : 0.f) * vb[m]; }
    else { x = va[m]; }
    w[t] = x;
  }
  __syncthreads();
  const u16* __restrict__ p = MT + (size_t)c*NN + (size_t)m0*2048 + n;
  float s = 0.f;
  #pragma unroll 4
  for (int m=0;m<64;m++)
    s += b2f(p[(size_t)m*2048]) * w[m];
  atomicAdd(&outv[c*2048 + n], s);
}

// ---- fused hw = h@gcn_w then PT[c][d][n] = bf16(rsqrt(max(rowsum,1))*hw[n][d]) ------
__global__ __launch_bounds__(256)
void k_hwpt(const float* __restrict__ h, const float* __restrict__ W,
            const float* __restrict__ rowsum, u16* __restrict__ PT){
  __shared__ float lh[8][256];
  int t = threadIdx.x;
  int n0 = blockIdx.x * 8;
  for (int idx = t; idx < 8*256; idx += 256)
    lh[idx >> 8][idx & 255] = h[(size_t)(n0 + (idx>>8))*256 + (idx&255)];
  __syncthreads();
  int d = t & 127, half = t >> 7;
  float acc[4];
  #pragma unroll
  for (int nn=0;nn<4;nn++) acc[nn] = 0.f;
  for (int k=0;k<256;k++){
    float wv = W[(size_t)k*128 + d];
    #pragma unroll
    for (int nn=0;nn<4;nn++) acc[nn] += lh[half*4+nn][k]*wv;
  }
  #pragma unroll
  for (int c=0;c<2;c++){
    ushort4 o;
    #pragma unroll
    for (int nn=0;nn<4;nn++){
      int n = n0 + half*4 + nn;
      float dv = rsqrtf(fmaxf(rowsum[c*2048 + n], 1.0f));
      ((u16*)&o)[nn] = f2b(dv * acc[nn]);
    }
    *(ushort4*)&PT[((size_t)c*128 + d)*2048 + n0 + half*4] = o;
  }
}

// ------- thin bt-GEMM split-K=8 (2-barrier loop), atomic f32 C: Agg += A @ Bt^T ------
__global__ __launch_bounds__(256, 2)
void k_gemm3(const u16* __restrict__ A, const u16* __restrict__ Bt, float* __restrict__ Agg){
  __shared__ u16 lA[128*64];
  __shared__ u16 lB[128*64];
  const int tid = threadIdx.x;
  const int bm = blockIdx.x, bk = blockIdx.y, cc = blockIdx.z;
  const u16* __restrict__ Ab = A + (size_t)cc*NN + (size_t)(bm*128)*2048 + bk*256;
  const u16* __restrict__ Bb = Bt + (size_t)cc*(128*2048) + bk*256;
  float* __restrict__ Cb = Agg + (size_t)cc*2048*128 + (size_t)(bm*128)*128;
  const int wid = tid >> 6, lane = tid & 63;
  const int wr = wid >> 1, wc = wid & 1;
  const int fl = lane & 15, fk = (lane >> 4) << 3;
  const int srow = (wid << 3) + (lane >> 3);
  const int scol = (lane & 7) << 3;

  f32x4 acc[4][4];
  const f32x4 zero = {0.f,0.f,0.f,0.f};
  #pragma unroll
  for (int i=0;i<4;i++)
    #pragma unroll
    for (int jj=0;jj<4;jj++) acc[i][jj] = zero;

  for (int k0 = 0; k0 < 256; k0 += 64){
    #pragma unroll
    for (int it = 0; it < 4; ++it){
      int r = it*32 + srow;
      __builtin_amdgcn_global_load_lds(
        (const __attribute__((address_space(1))) void*)(Ab + (size_t)r*2048 + k0 + scol),
        (__attribute__((address_space(3))) void*)(&lA[(it*32 + (wid<<3))*64]), 16, 0, 0);
      __builtin_amdgcn_global_load_lds(
        (const __attribute__((address_space(1))) void*)(Bb + (size_t)r*2048 + k0 + scol),
        (__attribute__((address_space(3))) void*)(&lB[(it*32 + (wid<<3))*64]), 16, 0, 0);
    }
    __syncthreads();
    #pragma unroll
    for (int ks = 0; ks < 2; ++ks){
      bf16x8 af[4], bfr[4];
      #pragma unroll
      for (int mi=0;mi<4;mi++)
        af[mi] = *reinterpret_cast<const bf16x8*>(&lA[(wr*64 + mi*16 + fl)*64 + ks*32 + fk]);
      #pragma unroll
      for (int ni=0;ni<4;ni++)
        bfr[ni] = *reinterpret_cast<const bf16x8*>(&lB[(wc*64 + ni*16 + fl)*64 + ks*32 + fk]);
      #pragma unroll
      for (int mi=0;mi<4;mi++)
        #pragma unroll
        for (int ni=0;ni<4;ni++)
          acc[mi][ni] = __builtin_amdgcn_mfma_f32_16x16x32_bf16(af[mi], bfr[ni], acc[mi][ni], 0, 0, 0);
    }
    __syncthreads();
  }
  const int rbase = (lane >> 4) << 2;
  #pragma unroll
  for (int mi=0;mi<4;mi++)
    #pragma unroll
    for (int ni=0;ni<4;ni++)
      #pragma unroll
      for (int r=0;r<4;r++)
        atomicAdd(&Cb[(size_t)(wr*64 + mi*16 + rbase + r)*128 + wc*64 + ni*16 + fl],
                  acc[mi][ni][r]);
}

// ---- Agg f32 [c][2048][128] (+ optional dinv1 row scale) -> transposed bf16 QT ------
template<bool SCALE>
__global__ __launch_bounds__(256)
void k_qt(const float* __restrict__ Agg, const float* __restrict__ deg1,
          u16* __restrict__ QT){
  __shared__ u16 lq[128][36];
  const int t = threadIdx.x;
  const int m0 = blockIdx.x * 32, c = blockIdx.y;
  const int d4 = (t & 31) * 4, mr = t >> 5;
  #pragma unroll
  for (int p4=0; p4<4; ++p4){
    const int m = m0 + p4*8 + mr;
    float4 s = *(const float4*)&Agg[((size_t)c*2048 + m)*128 + d4];
    if (SCALE){
      float dg = deg1[c*2048 + m];
      float di = dg > 0.f ? 1.f/dg : 0.f;
      s.x *= di; s.y *= di; s.z *= di; s.w *= di;
    }
    const int ml = p4*8 + mr;
    lq[d4+0][ml] = f2b(s.x); lq[d4+1][ml] = f2b(s.y);
    lq[d4+2][ml] = f2b(s.z); lq[d4+3][ml] = f2b(s.w);
  }
  __syncthreads();
  const int d = t >> 1, half = t & 1;
  u16* __restrict__ dst = QT + ((size_t)c*128 + d)*2048 + m0 + half*16;
  #pragma unroll
  for (int q=0;q<4;q++){
    ushort4 o;
    o.x = lq[d][half*16 + q*4 + 0];
    o.y = lq[d][half*16 + q*4 + 1];
    o.z = lq[d][half*16 + q*4 + 2];
    o.w = lq[d][half*16 + q*4 + 3];
    *(ushort4*)&dst[q*4] = o;
  }
}

// -------- head: Xc = relu(dinv2[c,m]*agg3 + gb); out = relu(Xc@W1+b1)@W2+b2 ----------
__global__ __launch_bounds__(256)
void k_head(const float* __restrict__ agg3, const float* __restrict__ deg2,
            const float* __restrict__ gb,
            const float* __restrict__ W1, const float* __restrict__ b1,
            const float* __restrict__ W2, const float* __restrict__ b2,
            float* __restrict__ out){
  __shared__ float lx[8][256];
  __shared__ float lt[8][132];
  int t = threadIdx.x;
  int n0 = blockIdx.x * 8;
  for (int idx = t; idx < 512; idx += 256){
    int row = idx >> 6;
    int q = idx & 63;
    int c = q >> 5, d4 = (q & 31) * 4;
    float dg = deg2[c*2048 + n0 + row];
    float di = dg > 0.f ? 1.f/dg : 0.f;
    float4 s = *(const float4*)&agg3[((size_t)c*2048 + n0 + row)*128 + d4];
    const float4 bv = *(const float4*)&gb[d4];
    s.x = fmaxf(s.x*di + bv.x, 0.f); s.y = fmaxf(s.y*di + bv.y, 0.f);
    s.z = fmaxf(s.z*di + bv.z, 0.f); s.w = fmaxf(s.w*di + bv.w, 0.f);
    *(float4*)&lx[row][c*128 + d4] = s;
  }
  __syncthreads();
  int d = t & 127, half = t >> 7;
  float acc[4];
  #pragma unroll
  for (int nn=0;nn<4;nn++) acc[nn] = 0.f;
  for (int k=0;k<256;k++){
    float wv = W1[(size_t)k*128 + d];
    #pragma unroll
    for (int nn=0;nn<4;nn++) acc[nn] += lx[half*4+nn][k]*wv;
  }
  float bb = b1[d];
  #pragma unroll
  for (int nn=0;nn<4;nn++){
    float v = acc[nn] + bb;
    lt[half*4+nn][d] = v > 0.f ? v : 0.f;
  }
  __syncthreads();
  if (t < 128){
    int row = t >> 4, q = t & 15;
    float s = b2[q];
    for (int dd=0; dd<128; dd++) s += lt[row][dd] * W2[(size_t)dd*16 + q];
    out[(size_t)(n0+row)*16 + q] = s;
  }
}

extern "C" void kernel_launch(void* const* d_in, const int* in_sizes, int n_in,
                              void* d_out, int out_size, void* d_ws, size_t ws_size,
                              hipStream_t stream){
  const float* A   = (const float*)d_in[0];
  const float* h   = (const float*)d_in[1];
  const float* w1  = (const float*)d_in[2];
  const float* w2  = (const float*)d_in[3];
  const float* wl  = (const float*)d_in[4];
  const float* gw  = (const float*)d_in[5];
  const float* gb  = (const float*)d_in[6];
  const float* l1w = (const float*)d_in[7];
  const float* l1b = (const float*)d_in[8];
  const float* l2w = (const float*)d_in[9];
  const float* l2b = (const float*)d_in[10];
  float* out = (float*)d_out;
  char* ws = (char*)d_ws;

  const size_t SZ = 2*NN*2;     // 16.78 MB (one bf16 [2][2048][2048])
  const size_t AGG = (size_t)2*2048*128*4;   // 2 MB
  u16*  A1T  = (u16*)(ws);
  u16*  A2T  = (u16*)(ws + 1*SZ);
  u16*  BT   = (u16*)(ws + 2*SZ);
  char* tail = ws + 3*SZ;
  u16*  PT     = (u16*)tail;                      // 1MB
  u16*  Q1T    = (u16*)(tail + 1048576);          // 1MB
  u16*  Q2T    = (u16*)(tail + 2*1048576);        // 1MB
  float* sA1   = (float*)(tail + 3*1048576);      // zeroed region starts here
  float* deg1  = sA1 + 4096;
  float* deg2  = deg1 + 4096;
  float* v1    = deg2 + 4096;
  float* v3    = v1 + 4096;
  float* rowsum= v3 + 4096;
  float* agg1  = rowsum + 4096;                   // 3 x 2MB
  float* agg2  = agg1 + 2*2048*128;
  float* agg3  = agg2 + 2*2048*128;
  const size_t ZBYTES = 6*4096*4 + 3*AGG;

  const size_t TOTAL = 3*SZ + 3*1048576 + ZBYTES;
  if (ws_size < TOTAL){ hipMemsetAsync(d_out, 0, (size_t)out_size*4, stream); return; }

  // fast custom zero (runtime fillBuffer measured ~48us for 6.4MB -- pathological)
  k_zero<<<1024, 256, 0, stream>>>((float4*)sA1, (int)(ZBYTES/16));

  // A -> A1T, A2T, BT + sA1 (colsum A1), deg2 (colsum B)
  k_mix<<<dim3(64,32), 256, 0, stream>>>(A, w1, w2, wl, A1T, A2T, BT, sA1, deg2);
  // merged: deg1 = sA1@A2 (row-dots)  ||  v1 = B@dinv2
  k_post1<<<1536, 256, 0, stream>>>(A2T, BT, sA1, deg2, deg1, v1);
  // rowsum chain: v3 = A2@(dinv1*v1) ; rowsum = A1@v3
  k_wsum<1><<<dim3(8,32,2), 256, 0, stream>>>(A2T, deg1, v1, v3);
  k_wsum<2><<<dim3(8,32,2), 256, 0, stream>>>(A1T, v3, v3, rowsum);
  // features: PT = dout * (h@gcn_w)^T
  k_hwpt<<<256, 256, 0, stream>>>(h, gw, rowsum, PT);
  // agg chain: Q1 = A1^T@P ; Q2 = dinv1*(A2^T@Q1) ; agg3 = B^T@Q2 ; (dinv2 in head)
  k_gemm3<<<dim3(16,8,2), 256, 0, stream>>>(A1T, PT, agg1);
  k_qt<false><<<dim3(64,2), 256, 0, stream>>>(agg1, deg1, Q1T);
  k_gemm3<<<dim3(16,8,2), 256, 0, stream>>>(A2T, Q1T, agg2);
  k_qt<true><<<dim3(64,2), 256, 0, stream>>>(agg2, deg1, Q2T);
  k_gemm3<<<dim3(16,8,2), 256, 0, stream>>>(BT, Q2T, agg3);
  k_head<<<256, 256, 0, stream>>>(agg3, deg2, gb, l1w, l1b, l2w, l2b, out);
}

// Round 16
// 149.079 us; speedup vs baseline: 1.0284x; 1.0284x over previous
//
#include <hip/hip_runtime.h>

typedef unsigned short u16;
typedef __attribute__((ext_vector_type(4))) float f32x4;
typedef __attribute__((ext_vector_type(8))) __bf16 bf16x8;
typedef __attribute__((ext_vector_type(8))) unsigned short us8;

#define NN (2048ull*2048ull)

// Tile-linear layout for big T-matrices: 32m x 64n tiles.
// addr(m,n) = ((n>>6)*64 + (m>>5))*2048 + (m&31)*64 + (n&63)

__device__ __forceinline__ u16 f2b(float x){
  union { float f; unsigned u; } v; v.f = x;
  unsigned r = v.u + 0x7FFFu + ((v.u >> 16) & 1u);
  return (u16)(r >> 16);
}
__device__ __forceinline__ float b2f(u16 x){
  union { unsigned u; float f; } v; v.u = ((unsigned)x) << 16; return v.f;
}

// ---- fast zero of the atomic-target region ----
__global__ __launch_bounds__(256)
void k_zero(float4* __restrict__ p, int n4){
  const float4 z = {0.f,0.f,0.f,0.f};
  for (int i = blockIdx.x*256 + threadIdx.x; i < n4; i += gridDim.x*256)
    p[i] = z;
}

// ---- fused 3-way mix of A -> A1T, A2T, BT (tile-linear bf16 [2][...]) + col-sums.
//      v11: v9 compute, stores = one contiguous 4KB blob per (s,c) per block. --------
__global__ __launch_bounds__(256)
void k_mix(const float* __restrict__ A,
           const float* __restrict__ w1, const float* __restrict__ w2,
           const float* __restrict__ wl,
           u16* __restrict__ A1T, u16* __restrict__ A2T, u16* __restrict__ BT,
           float* __restrict__ sA1, float* __restrict__ deg2){
  __shared__ u16 lt[4][32][68];
  const int t = threadIdx.x;
  const int mg = t & 7, ng = t >> 3;                 // read: 8 m-groups x 32 n-groups
  const int m0 = blockIdx.x * 32, n0 = blockIdx.y * 64;
  float f[3][2][5];
  #pragma unroll
  for (int s=0;s<3;s++){
    const float* w = (s==0) ? w1 : (s==1) ? w2 : wl;
    #pragma unroll
    for (int c=0;c<2;c++){
      float m = -1e30f;
      #pragma unroll
      for (int e=0;e<5;e++) m = fmaxf(m, w[e*2+c]);
      float sum = 0.f;
      #pragma unroll
      for (int e=0;e<5;e++){ f[s][c][e] = __expf(w[e*2+c]-m); sum += f[s][c][e]; }
      float inv = 1.f/sum;
      #pragma unroll
      for (int e=0;e<5;e++) f[s][c][e] *= inv;
    }
  }

  // compute 6 (s,c) micro-tiles (2n x 4m) into registers; component j = m-dir
  ushort4 reg[6][2];
  #pragma unroll
  for (int rr=0; rr<2; ++rr){
    const int nl = ng*2 + rr;
    const size_t off = (size_t)(n0+nl)*2048 + m0 + mg*4;
    float4 a0 = *(const float4*)&A[off];
    float4 a1 = *(const float4*)&A[NN + off];
    float4 a2 = *(const float4*)&A[2*NN + off];
    float4 a3 = *(const float4*)&A[3*NN + off];
    float4 a4 = *(const float4*)&A[4*NN + off];
    float ax[4][5] = {{a0.x,a1.x,a2.x,a3.x,a4.x},
                      {a0.y,a1.y,a2.y,a3.y,a4.y},
                      {a0.z,a1.z,a2.z,a3.z,a4.z},
                      {a0.w,a1.w,a2.w,a3.w,a4.w}};
    #pragma unroll
    for (int c=0;c<2;c++){
      #pragma unroll
      for (int j=0;j<4;j++){
        float s1=0.f,s2=0.f,s3=0.f;
        #pragma unroll
        for (int e=0;e<5;e++){
          s1 += ax[j][e]*f[0][c][e];
          s2 += ax[j][e]*f[1][c][e];
          s3 += ax[j][e]*f[2][c][e];
        }
        ((u16*)&reg[0+c][rr])[j] = f2b(s1);
        ((u16*)&reg[2+c][rr])[j] = f2b(s2);
        ((u16*)&reg[4+c][rr])[j] = f2b(s3);
      }
    }
  }

  const int row = t >> 3, seg = t & 7;
  // tile-linear: this block's tile = (by*64 + bx); thread's slot = t*8 (4KB/blob)
  const size_t tb = (((size_t)blockIdx.y*64 + blockIdx.x) << 11) + (size_t)t*8;

  // phase B1: A1 (c0,c1), A2 (c0,c1) -> buffers 0..3, m-major (in-reg transpose)
  #pragma unroll
  for (int sc=0; sc<4; ++sc){
    #pragma unroll
    for (int j=0;j<4;j++){
      ushort2 o;
      o.x = ((const u16*)&reg[sc][0])[j];
      o.y = ((const u16*)&reg[sc][1])[j];
      *(ushort2*)&lt[sc][mg*4+j][ng*2] = o;
    }
  }
  __syncthreads();
  // phase C1: store A1T (+sA1) and A2T -- fully sequential 4KB blobs
  #pragma unroll
  for (int sc=0; sc<4; ++sc){
    u16* __restrict__ dst = (sc<2) ? A1T : A2T;
    const int c = sc & 1;
    us8 v0 = *(const us8*)&lt[sc][row][seg*8];
    *(us8*)&dst[(size_t)c*NN + tb] = v0;
    if (sc < 2){
      float part = 0.f;
      #pragma unroll
      for (int q=0;q<8;q++) part += b2f(v0[q]);
      part += __shfl_xor(part, 1); part += __shfl_xor(part, 2);
      part += __shfl_xor(part, 4);
      if (seg == 0) atomicAdd(&sA1[c*2048 + m0 + row], part);
    }
  }
  __syncthreads();
  // phase B2: B (c0,c1) -> buffers 0,1
  #pragma unroll
  for (int c=0;c<2;c++){
    #pragma unroll
    for (int j=0;j<4;j++){
      ushort2 o;
      o.x = ((const u16*)&reg[4+c][0])[j];
      o.y = ((const u16*)&reg[4+c][1])[j];
      *(ushort2*)&lt[c][mg*4+j][ng*2] = o;
    }
  }
  __syncthreads();
  // phase C2: store BT (+deg2)
  #pragma unroll
  for (int c=0;c<2;c++){
    us8 v0 = *(const us8*)&lt[c][row][seg*8];
    *(us8*)&BT[(size_t)c*NN + tb] = v0;
    float part = 0.f;
    #pragma unroll
    for (int q=0;q<8;q++) part += b2f(v0[q]);
    part += __shfl_xor(part, 1); part += __shfl_xor(part, 2);
    part += __shfl_xor(part, 4);
    if (seg == 0) atomicAdd(&deg2[c*2048 + m0 + row], part);
  }
}

// ---- merged: blocks 0..1023 -> deg1[c][j] = sum_k sA1[c][k]*A2T[c][j][k]
//              blocks 1024..1535 -> v1[c][n] += sum_m BT[c][m][n]*inv(deg2[c][m]) -----
__global__ __launch_bounds__(256)
void k_post1(const u16* __restrict__ A2T, const u16* __restrict__ BT,
             const float* __restrict__ sA1, const float* __restrict__ deg2,
             float* __restrict__ deg1, float* __restrict__ v1){
  const int b = blockIdx.x;
  const int t = threadIdx.x;
  if (b < 1024){
    const int g = b*4 + (t >> 6);
    const int lane = t & 63;
    const int c = g >> 11, j = g & 2047;
    // tile-linear row scan: nt = it*8 + (lane>>3), mt = j>>5
    const u16* __restrict__ base = A2T + (size_t)c*NN
        + ((size_t)(j>>5) << 11) + (size_t)((j&31) << 6)
        + ((size_t)(lane>>3) << 17) + (size_t)(lane&7)*8;
    const float* __restrict__ sv = sA1 + c*2048;
    float s = 0.f;
    #pragma unroll
    for (int it=0; it<4; ++it){
      const int k = it*512 + lane*8;
      us8 v = *(const us8*)&base[(size_t)it << 20];
      const float4 f0 = *(const float4*)&sv[k];
      const float4 f1 = *(const float4*)&sv[k+4];
      s += b2f(v[0])*f0.x + b2f(v[1])*f0.y + b2f(v[2])*f0.z + b2f(v[3])*f0.w
         + b2f(v[4])*f1.x + b2f(v[5])*f1.y + b2f(v[6])*f1.z + b2f(v[7])*f1.w;
    }
    s += __shfl_xor(s, 1);  s += __shfl_xor(s, 2);  s += __shfl_xor(s, 4);
    s += __shfl_xor(s, 8);  s += __shfl_xor(s, 16); s += __shfl_xor(s, 32);
    if (lane == 0) deg1[c*2048 + j] = s;
  } else {
    __shared__ float w[64];
    const int bx = b - 1024;
    const int x = bx & 7, y = (bx >> 3) & 31, c = bx >> 8;
    const int n = x * 256 + t;
    const int m0 = y * 64;
    if (t < 64){
      float d = deg2[c*2048 + m0 + t];
      w[t] = d > 0.f ? 1.f/d : 0.f;
    }
    __syncthreads();
    const u16* __restrict__ base = BT + (size_t)c*NN
        + ((size_t)((n>>6)*64 + (m0>>5)) << 11) + (n & 63);
    float s = 0.f;
    #pragma unroll 4
    for (int m=0;m<32;m++)
      s += b2f(base[m*64]) * w[m];
    #pragma unroll 4
    for (int m=0;m<32;m++)
      s += b2f(base[2048 + m*64]) * w[32+m];
    atomicAdd(&v1[c*2048 + n], s);
  }
}

// ---- weighted column-sum over rows of MT (tile-linear): 64-row strips ---------------
template<int MODE>
__global__ __launch_bounds__(256)
void k_wsum(const u16* __restrict__ MT, const float* __restrict__ va,
            const float* __restrict__ vb, float* __restrict__ outv){
  __shared__ float w[64];
  const int t = threadIdx.x;
  const int n = blockIdx.x * 256 + t;
  const int m0 = blockIdx.y * 64;
  const int c = blockIdx.z;
  if (t < 64){
    const int m = c*2048 + m0 + t;
    float x;
    if (MODE == 1){ float d = va[m]; x = (d > 0.f ? 1.f/d : 0.f) * vb[m]; }
    else { x = va[m]; }
    w[t] = x;
  }
  __syncthreads();
  const u16* __restrict__ base = MT + (size_t)c*NN
      + ((size_t)((n>>6)*64 + (m0>>5)) << 11) + (n & 63);
  float s = 0.f;
  #pragma unroll 4
  for (int m=0;m<32;m++)
    s += b2f(base[m*64]) * w[m];
  #pragma unroll 4
  for (int m=0;m<32;m++)
    s += b2f(base[2048 + m*64]) * w[32+m];
  atomicAdd(&outv[c*2048 + n], s);
}

// ---- fused hw = h@gcn_w then PT[c][d][n] = bf16(rsqrt(max(rowsum,1))*hw[n][d]) ------
// PT stays ROW-major [c][128][2048]
__global__ __launch_bounds__(256)
void k_hwpt(const float* __restrict__ h, const float* __restrict__ W,
            const float* __restrict__ rowsum, u16* __restrict__ PT){
  __shared__ float lh[8][256];
  int t = threadIdx.x;
  int n0 = blockIdx.x * 8;
  for (int idx = t; idx < 8*256; idx += 256)
    lh[idx >> 8][idx & 255] = h[(size_t)(n0 + (idx>>8))*256 + (idx&255)];
  __syncthreads();
  int d = t & 127, half = t >> 7;
  float acc[4];
  #pragma unroll
  for (int nn=0;nn<4;nn++) acc[nn] = 0.f;
  for (int k=0;k<256;k++){
    float wv = W[(size_t)k*128 + d];
    #pragma unroll
    for (int nn=0;nn<4;nn++) acc[nn] += lh[half*4+nn][k]*wv;
  }
  #pragma unroll
  for (int c=0;c<2;c++){
    ushort4 o;
    #pragma unroll
    for (int nn=0;nn<4;nn++){
      int n = n0 + half*4 + nn;
      float dv = rsqrtf(fmaxf(rowsum[c*2048 + n], 1.0f));
      ((u16*)&o)[nn] = f2b(dv * acc[nn]);
    }
    *(ushort4*)&PT[((size_t)c*128 + d)*2048 + n0 + half*4] = o;
  }
}

// ------- thin bt-GEMM split-K=8, atomic f32 C: Agg += A(tile-linear) @ Bt(row-major)^T
__global__ __launch_bounds__(256, 2)
void k_gemm3(const u16* __restrict__ A, const u16* __restrict__ Bt, float* __restrict__ Agg){
  __shared__ u16 lA[128*64];
  __shared__ u16 lB[128*64];
  const int tid = threadIdx.x;
  const int bm = blockIdx.x, bk = blockIdx.y, cc = blockIdx.z;
  const u16* __restrict__ Bb = Bt + (size_t)cc*(128*2048) + bk*256;
  float* __restrict__ Cb = Agg + (size_t)cc*2048*128 + (size_t)(bm*128)*128;
  const int wid = tid >> 6, lane = tid & 63;
  const int wr = wid >> 1, wc = wid & 1;
  const int fl = lane & 15, fk = (lane >> 4) << 3;
  const int srow = (wid << 3) + (lane >> 3);   // 0..31
  const int scol = (lane & 7) << 3;

  f32x4 acc[4][4];
  const f32x4 zero = {0.f,0.f,0.f,0.f};
  #pragma unroll
  for (int i=0;i<4;i++)
    #pragma unroll
    for (int jj=0;jj<4;jj++) acc[i][jj] = zero;

  for (int k0 = 0; k0 < 256; k0 += 64){
    #pragma unroll
    for (int it = 0; it < 4; ++it){
      // A operand: tile-linear. m = bm*128 + it*32 + srow ; n = bk*256 + k0 + scol
      const u16* srcA = A + (size_t)cc*NN
          + (((size_t)((bk*4 + (k0>>6))*64 + bm*4 + it)) << 11)
          + (srow << 6) + scol;
      __builtin_amdgcn_global_load_lds(
        (const __attribute__((address_space(1))) void*)srcA,
        (__attribute__((address_space(3))) void*)(&lA[(it*32 + (wid<<3))*64]), 16, 0, 0);
      int r = it*32 + srow;
      __builtin_amdgcn_global_load_lds(
        (const __attribute__((address_space(1))) void*)(Bb + (size_t)r*2048 + k0 + scol),
        (__attribute__((address_space(3))) void*)(&lB[(it*32 + (wid<<3))*64]), 16, 0, 0);
    }
    __syncthreads();
    #pragma unroll
    for (int ks = 0; ks < 2; ++ks){
      bf16x8 af[4], bfr[4];
      #pragma unroll
      for (int mi=0;mi<4;mi++)
        af[mi] = *reinterpret_cast<const bf16x8*>(&lA[(wr*64 + mi*16 + fl)*64 + ks*32 + fk]);
      #pragma unroll
      for (int ni=0;ni<4;ni++)
        bfr[ni] = *reinterpret_cast<const bf16x8*>(&lB[(wc*64 + ni*16 + fl)*64 + ks*32 + fk]);
      #pragma unroll
      for (int mi=0;mi<4;mi++)
        #pragma unroll
        for (int ni=0;ni<4;ni++)
          acc[mi][ni] = __builtin_amdgcn_mfma_f32_16x16x32_bf16(af[mi], bfr[ni], acc[mi][ni], 0, 0, 0);
    }
    __syncthreads();
  }
  const int rbase = (lane >> 4) << 2;
  #pragma unroll
  for (int mi=0;mi<4;mi++)
    #pragma unroll
    for (int ni=0;ni<4;ni++)
      #pragma unroll
      for (int r=0;r<4;r++)
        atomicAdd(&Cb[(size_t)(wr*64 + mi*16 + rbase + r)*128 + wc*64 + ni*16 + fl],
                  acc[mi][ni][r]);
}

// ---- Agg f32 [c][2048][128] (+ optional dinv1 row scale) -> transposed bf16 QT ------
// QT stays ROW-major [c][128][2048]
template<bool SCALE>
__global__ __launch_bounds__(256)
void k_qt(const float* __restrict__ Agg, const float* __restrict__ deg1,
          u16* __restrict__ QT){
  __shared__ u16 lq[128][36];
  const int t = threadIdx.x;
  const int m0 = blockIdx.x * 32, c = blockIdx.y;
  const int d4 = (t & 31) * 4, mr = t >> 5;
  #pragma unroll
  for (int p4=0; p4<4; ++p4){
    const int m = m0 + p4*8 + mr;
    float4 s = *(const float4*)&Agg[((size_t)c*2048 + m)*128 + d4];
    if (SCALE){
      float dg = deg1[c*2048 + m];
      float di = dg > 0.f ? 1.f/dg : 0.f;
      s.x *= di; s.y *= di; s.z *= di; s.w *= di;
    }
    const int ml = p4*8 + mr;
    lq[d4+0][ml] = f2b(s.x); lq[d4+1][ml] = f2b(s.y);
    lq[d4+2][ml] = f2b(s.z); lq[d4+3][ml] = f2b(s.w);
  }
  __syncthreads();
  const int d = t >> 1, half = t & 1;
  u16* __restrict__ dst = QT + ((size_t)c*128 + d)*2048 + m0 + half*16;
  #pragma unroll
  for (int q=0;q<4;q++){
    ushort4 o;
    o.x = lq[d][half*16 + q*4 + 0];
    o.y = lq[d][half*16 + q*4 + 1];
    o.z = lq[d][half*16 + q*4 + 2];
    o.w = lq[d][half*16 + q*4 + 3];
    *(ushort4*)&dst[q*4] = o;
  }
}

// -------- head: Xc = relu(dinv2[c,m]*agg3 + gb); out = relu(Xc@W1+b1)@W2+b2 ----------
__global__ __launch_bounds__(256)
void k_head(const float* __restrict__ agg3, const float* __restrict__ deg2,
            const float* __restrict__ gb,
            const float* __restrict__ W1, const float* __restrict__ b1,
            const float* __restrict__ W2, const float* __restrict__ b2,
            float* __restrict__ out){
  __shared__ float lx[8][256];
  __shared__ float lt[8][132];
  int t = threadIdx.x;
  int n0 = blockIdx.x * 8;
  for (int idx = t; idx < 512; idx += 256){
    int row = idx >> 6;
    int q = idx & 63;
    int c = q >> 5, d4 = (q & 31) * 4;
    float dg = deg2[c*2048 + n0 + row];
    float di = dg > 0.f ? 1.f/dg : 0.f;
    float4 s = *(const float4*)&agg3[((size_t)c*2048 + n0 + row)*128 + d4];
    const float4 bv = *(const float4*)&gb[d4];
    s.x = fmaxf(s.x*di + bv.x, 0.f); s.y = fmaxf(s.y*di + bv.y, 0.f);
    s.z = fmaxf(s.z*di + bv.z, 0.f); s.w = fmaxf(s.w*di + bv.w, 0.f);
    *(float4*)&lx[row][c*128 + d4] = s;
  }
  __syncthreads();
  int d = t & 127, half = t >> 7;
  float acc[4];
  #pragma unroll
  for (int nn=0;nn<4;nn++) acc[nn] = 0.f;
  for (int k=0;k<256;k++){
    float wv = W1[(size_t)k*128 + d];
    #pragma unroll
    for (int nn=0;nn<4;nn++) acc[nn] += lx[half*4+nn][k]*wv;
  }
  float bb = b1[d];
  #pragma unroll
  for (int nn=0;nn<4;nn++){
    float v = acc[nn] + bb;
    lt[half*4+nn][d] = v > 0.f ? v : 0.f;
  }
  __syncthreads();
  if (t < 128){
    int row = t >> 4, q = t & 15;
    float s = b2[q];
    for (int dd=0; dd<128; dd++) s += lt[row][dd] * W2[(size_t)dd*16 + q];
    out[(size_t)(n0+row)*16 + q] = s;
  }
}

extern "C" void kernel_launch(void* const* d_in, const int* in_sizes, int n_in,
                              void* d_out, int out_size, void* d_ws, size_t ws_size,
                              hipStream_t stream){
  const float* A   = (const float*)d_in[0];
  const float* h   = (const float*)d_in[1];
  const float* w1  = (const float*)d_in[2];
  const float* w2  = (const float*)d_in[3];
  const float* wl  = (const float*)d_in[4];
  const float* gw  = (const float*)d_in[5];
  const float* gb  = (const float*)d_in[6];
  const float* l1w = (const float*)d_in[7];
  const float* l1b = (const float*)d_in[8];
  const float* l2w = (const float*)d_in[9];
  const float* l2b = (const float*)d_in[10];
  float* out = (float*)d_out;
  char* ws = (char*)d_ws;

  const size_t SZ = 2*NN*2;     // 16.78 MB (one bf16 [2][...] tile-linear matrix)
  const size_t AGG = (size_t)2*2048*128*4;   // 2 MB
  u16*  A1T  = (u16*)(ws);
  u16*  A2T  = (u16*)(ws + 1*SZ);
  u16*  BT   = (u16*)(ws + 2*SZ);
  char* tail = ws + 3*SZ;
  u16*  PT     = (u16*)tail;                      // 1MB (row-major)
  u16*  Q1T    = (u16*)(tail + 1048576);          // 1MB (row-major)
  u16*  Q2T    = (u16*)(tail + 2*1048576);        // 1MB (row-major)
  float* sA1   = (float*)(tail + 3*1048576);      // zeroed region starts here
  float* deg1  = sA1 + 4096;
  float* deg2  = deg1 + 4096;
  float* v1    = deg2 + 4096;
  float* v3    = v1 + 4096;
  float* rowsum= v3 + 4096;
  float* agg1  = rowsum + 4096;                   // 3 x 2MB
  float* agg2  = agg1 + 2*2048*128;
  float* agg3  = agg2 + 2*2048*128;
  const size_t ZBYTES = 6*4096*4 + 3*AGG;

  const size_t TOTAL = 3*SZ + 3*1048576 + ZBYTES;
  if (ws_size < TOTAL){ hipMemsetAsync(d_out, 0, (size_t)out_size*4, stream); return; }

  k_zero<<<1024, 256, 0, stream>>>((float4*)sA1, (int)(ZBYTES/16));

  // A -> A1T, A2T, BT (tile-linear) + sA1 (colsum A1), deg2 (colsum B)
  k_mix<<<dim3(64,32), 256, 0, stream>>>(A, w1, w2, wl, A1T, A2T, BT, sA1, deg2);
  // merged: deg1 = sA1@A2 (row-dots)  ||  v1 = B@dinv2
  k_post1<<<1536, 256, 0, stream>>>(A2T, BT, sA1, deg2, deg1, v1);
  // rowsum chain: v3 = A2@(dinv1*v1) ; rowsum = A1@v3
  k_wsum<1><<<dim3(8,32,2), 256, 0, stream>>>(A2T, deg1, v1, v3);
  k_wsum<2><<<dim3(8,32,2), 256, 0, stream>>>(A1T, v3, v3, rowsum);
  // features: PT = dout * (h@gcn_w)^T
  k_hwpt<<<256, 256, 0, stream>>>(h, gw, rowsum, PT);
  // agg chain: Q1 = A1^T@P ; Q2 = dinv1*(A2^T@Q1) ; agg3 = B^T@Q2 ; (dinv2 in head)
  k_gemm3<<<dim3(16,8,2), 256, 0, stream>>>(A1T, PT, agg1);
  k_qt<false><<<dim3(64,2), 256, 0, stream>>>(agg1, deg1, Q1T);
  k_gemm3<<<dim3(16,8,2), 256, 0, stream>>>(A2T, Q1T, agg2);
  k_qt<true><<<dim3(64,2), 256, 0, stream>>>(agg2, deg1, Q2T);
  k_gemm3<<<dim3(16,8,2), 256, 0, stream>>>(BT, Q2T, agg3);
  k_head<<<256, 256, 0, stream>>>(agg3, deg2, gb, l1w, l1b, l2w, l2b, out);
}